// Round 8
// baseline (481.181 us; speedup 1.0000x reference)
//
#include <hip/hip_runtime.h>
#include <cstdint>
#include <cstddef>

#define NFEAT 512
#define NH1   256
#define NH2   128

#define P_CHUNKS 128          // edge chunks for privatized histogram
#define HHALF    25088        // nodes per half (2*HHALF = 50176 >= N)
#define NP       (2 * HHALF)  // padded node count in hist rows
#define HPB      1024         // threads per hist/place block (16 waves)

typedef __attribute__((ext_vector_type(8))) short short8;
typedef __attribute__((ext_vector_type(4))) float float4v;

__device__ __forceinline__ unsigned short f2bf(float f) {
    unsigned int u = __float_as_uint(f);
    u += 0x7fffu + ((u >> 16) & 1u);   // round-to-nearest-even
    return (unsigned short)(u >> 16);
}
__device__ __forceinline__ float bf2f(unsigned short u) {
    return __uint_as_float(((unsigned int)u) << 16);
}

__device__ __forceinline__ void load_lds16(const void* g, void* l) {
    __builtin_amdgcn_global_load_lds(
        (const __attribute__((address_space(1))) void*)g,
        (__attribute__((address_space(3))) void*)l, 16, 0, 0);
}

// ---------------- CSR build: LDS-privatized counting sort ----------------
__global__ __launch_bounds__(HPB) void k_hist_cvtw(
    const int* __restrict__ dst, int* __restrict__ hist,
    const float* __restrict__ W1, unsigned short* __restrict__ W1t,
    const float* __restrict__ W2, unsigned short* __restrict__ W2t,
    int E, int CE, int HB) {
    __shared__ int lh[HHALF];
    if (blockIdx.x >= HB) {   // weight-conversion blocks (uniform branch)
        const int i = (blockIdx.x - HB) * HPB + (int)threadIdx.x;
        const int T1 = NFEAT * NH1;
        const int T2 = NH1 * NH2;
        if (i < T1) {
            const int k = i / NH1, n = i % NH1;
            W1t[(size_t)n * NFEAT + k] = f2bf(W1[i]);
        } else if (i < T1 + T2) {
            const int j = i - T1;
            const int k = j / NH2, n = j % NH2;
            W2t[(size_t)n * NH1 + k] = f2bf(W2[j]);
        }
        return;
    }
    const int c    = blockIdx.x >> 1;
    const int hf   = blockIdx.x & 1;
    const int base = hf * HHALF;
    for (int i = threadIdx.x; i < HHALF; i += HPB) lh[i] = 0;
    __syncthreads();
    const int lo = c * CE;
    const int hi = lo + CE < E ? lo + CE : E;
    for (int e = lo + (int)threadIdx.x; e < hi; e += HPB) {
        const int d = dst[e] - base;
        if ((unsigned)d < (unsigned)HHALF) atomicAdd(&lh[d], 1);
    }
    __syncthreads();
    int* outp = hist + (size_t)c * NP + base;
    for (int i = threadIdx.x; i < HHALF; i += HPB) outp[i] = lh[i];
}

// Fused: column-reduce hist -> degi, dinv ; block partial sums -> blocksums.
__global__ __launch_bounds__(256) void k_redscan1(
    const int* __restrict__ hist, int* __restrict__ degi,
    float* __restrict__ dinv, int* __restrict__ blocksums, int N) {
    __shared__ int red[256];
    const int t = threadIdx.x;
    const int d = blockIdx.x * 256 + t;
    int s = 0;
    if (d < N) {
#pragma unroll 8
        for (int c = 0; c < P_CHUNKS; ++c) s += hist[(size_t)c * NP + d];
        degi[d] = s;
        dinv[d] = rsqrtf((float)(s + 1));   // +1 = self-loop
    }
    red[t] = s;
    __syncthreads();
    for (int off = 128; off > 0; off >>= 1) {
        if (t < off) red[t] += red[t + off];
        __syncthreads();
    }
    if (t == 0) blocksums[blockIdx.x] = red[0];
}

__global__ __launch_bounds__(1024) void k_scan2(
    const int* __restrict__ blocksums, int* __restrict__ blockoffs,
    int* __restrict__ row_start, int nb, int N) {
    __shared__ int sm[1024];
    const int t = threadIdx.x;
    const int v = (t < nb) ? blocksums[t] : 0;
    sm[t] = v;
    __syncthreads();
    for (int off = 1; off < 1024; off <<= 1) {
        const int x = (t >= off) ? sm[t - off] : 0;
        __syncthreads();
        sm[t] += x;
        __syncthreads();
    }
    if (t < nb) blockoffs[t] = sm[t] - v;
    if (t == 1023) row_start[N] = sm[1023];
}

// Fused: final scan -> row_start[d], then in-place column exclusive scan of
// hist[c][d] into global base offsets.
__global__ __launch_bounds__(256) void k_scan3off(
    const int* __restrict__ degi, const int* __restrict__ blockoffs,
    int* __restrict__ row_start, int* __restrict__ hist, int N) {
    __shared__ int tsum[256];
    const int t = threadIdx.x;
    const int d = blockIdx.x * 256 + t;
    const int v = (d < N) ? degi[d] : 0;
    tsum[t] = v;
    __syncthreads();
    for (int off = 1; off < 256; off <<= 1) {
        const int x = (t >= off) ? tsum[t - off] : 0;
        __syncthreads();
        tsum[t] += x;
        __syncthreads();
    }
    if (d < N) {
        int run = blockoffs[blockIdx.x] + tsum[t] - v;   // exclusive prefix
        row_start[d] = run;
        for (int c = 0; c < P_CHUNKS; ++c) {
            int* p = &hist[(size_t)c * NP + d];
            const int tt = *p;
            *p = run;
            run += tt;
        }
    }
}

// Phase E: place edges. LDS cursor atomics only; plain scattered stores.
__global__ __launch_bounds__(HPB) void k_place(const int* __restrict__ src,
                                               const int* __restrict__ dst,
                                               const int* __restrict__ hist,
                                               int* __restrict__ csr_src, int E, int CE) {
    __shared__ int lcur[HHALF];
    const int c    = blockIdx.x >> 1;
    const int hf   = blockIdx.x & 1;
    const int base = hf * HHALF;
    const int* offp = hist + (size_t)c * NP + base;
    for (int i = threadIdx.x; i < HHALF; i += HPB) lcur[i] = offp[i];
    __syncthreads();
    const int lo = c * CE;
    const int hi = lo + CE < E ? lo + CE : E;
    for (int e = lo + (int)threadIdx.x; e < hi; e += HPB) {
        const int d = dst[e] - base;
        if ((unsigned)d < (unsigned)HHALF) {
            const int p = atomicAdd(&lcur[d], 1);   // LDS atomic (fast)
            csr_src[p] = src[e];
        }
    }
}

// ---------------- fused layer-1 GEMM: h = bf16((x*dinv) @ W1) ----------------
__global__ __launch_bounds__(512) void gemm_x_fused(
    const float* __restrict__ x, const float* __restrict__ dinv,
    const unsigned short* __restrict__ Bt, unsigned short* __restrict__ C,
    int Nrows, int K) {
    __shared__ unsigned short As[128 * 32];   //  8 KB
    __shared__ unsigned short Bs[256 * 32];   // 16 KB
    const int t    = threadIdx.x;
    const int wave = t >> 6, lane = t & 63;
    const int row0 = blockIdx.x * 128;
    const int quad = lane >> 4, l15 = lane & 15;
    const int wm = (wave >> 2) * 64;          // 0 / 64
    const int wn = (wave & 3) * 64;           // 0 / 64 / 128 / 192

    const int arow = t >> 2;
    const int ak   = (t & 3) * 8;
    const int gr   = (row0 + arow < Nrows) ? row0 + arow : Nrows - 1;  // clamp pad rows
    const float wd = dinv[gr];
    const float* gx = x + (size_t)gr * K + ak;
    unsigned short* lA = &As[arow * 32 + ak];                 // byte off = t*16 (linear)

    const int brow = t >> 2;                  // 0..127 (seg2: +128)
    const int bk   = (t & 3) * 8;
    const unsigned short* gB0 = Bt + (size_t)brow * K + bk;
    const unsigned short* gB1 = Bt + (size_t)(128 + brow) * K + bk;
    unsigned short* lB0 = &Bs[wave * 512];            // wave-uniform base + lane*16
    unsigned short* lB1 = &Bs[128 * 32 + wave * 512];

    float4v acc[4][4] = {};

    for (int k0 = 0; k0 < K; k0 += 32) {
        __syncthreads();
        load_lds16(gB0 + k0, lB0);
        load_lds16(gB1 + k0, lB1);
        const float4 v0 = *(const float4*)(gx + k0);
        const float4 v1 = *(const float4*)(gx + k0 + 4);
        short8 o;
        o[0] = (short)f2bf(v0.x * wd); o[1] = (short)f2bf(v0.y * wd);
        o[2] = (short)f2bf(v0.z * wd); o[3] = (short)f2bf(v0.w * wd);
        o[4] = (short)f2bf(v1.x * wd); o[5] = (short)f2bf(v1.y * wd);
        o[6] = (short)f2bf(v1.z * wd); o[7] = (short)f2bf(v1.w * wd);
        *(short8*)lA = o;                                   // 16B ds_write
        __syncthreads();

        short8 a[4], b[4];
#pragma unroll
        for (int i = 0; i < 4; ++i) {
            a[i] = *(const short8*)&As[(wm + i * 16 + l15) * 32 + quad * 8];
            b[i] = *(const short8*)&Bs[(wn + i * 16 + l15) * 32 + quad * 8];
        }
#pragma unroll
        for (int mt = 0; mt < 4; ++mt)
#pragma unroll
            for (int nt = 0; nt < 4; ++nt)
                acc[mt][nt] = __builtin_amdgcn_mfma_f32_16x16x32_bf16(
                    a[mt], b[nt], acc[mt][nt], 0, 0, 0);
    }

    // C/D layout: col = lane&15, row = (lane>>4)*4 + reg   [m89-verified]
#pragma unroll
    for (int mt = 0; mt < 4; ++mt) {
#pragma unroll
        for (int nt = 0; nt < 4; ++nt) {
            const int c = wn + nt * 16 + l15;
#pragma unroll
            for (int r = 0; r < 4; ++r) {
                const int row = row0 + wm + mt * 16 + quad * 4 + r;
                C[(size_t)row * NH1 + c] = f2bf(acc[mt][nt][r]);
            }
        }
    }
}

// ---------------- bf16 MFMA GEMM (layer 2) ----------------
__global__ __launch_bounds__(256) void gemm_bf16(
    const unsigned short* __restrict__ A, const unsigned short* __restrict__ Bt,
    unsigned short* __restrict__ C, int N, int K) {
    __shared__ unsigned short As[128 * 32];
    __shared__ unsigned short Bs[128 * 32];
    const int t    = threadIdx.x;
    const int wave = t >> 6, lane = t & 63;
    const int row0 = blockIdx.y * 128, col0 = blockIdx.x * 128;
    const int wm = (wave >> 1) * 64, wn = (wave & 1) * 64;
    const int sr = lane >> 2;
    const int sk = (lane & 3) * 8;
    const int quad = lane >> 4, l15 = lane & 15;

    const int ca = wave * 2;
    const unsigned short* gA0 = A  + (size_t)(row0 + ca * 16 + sr) * K + sk;
    const unsigned short* gA1 = gA0 + (size_t)16 * K;
    const unsigned short* gB0 = Bt + (size_t)(col0 + ca * 16 + sr) * K + sk;
    const unsigned short* gB1 = gB0 + (size_t)16 * K;
    unsigned short* lA0 = &As[ca * 512];
    unsigned short* lA1 = &As[(ca + 1) * 512];
    unsigned short* lB0 = &Bs[ca * 512];
    unsigned short* lB1 = &Bs[(ca + 1) * 512];

    float4v acc[4][4] = {};

    for (int k0 = 0; k0 < K; k0 += 32) {
        __syncthreads();
        load_lds16(gA0 + k0, lA0);
        load_lds16(gA1 + k0, lA1);
        load_lds16(gB0 + k0, lB0);
        load_lds16(gB1 + k0, lB1);
        __syncthreads();

        short8 a[4], b[4];
#pragma unroll
        for (int i = 0; i < 4; ++i) {
            a[i] = *(const short8*)&As[(wm + i * 16 + l15) * 32 + quad * 8];
            b[i] = *(const short8*)&Bs[(wn + i * 16 + l15) * 32 + quad * 8];
        }
#pragma unroll
        for (int mt = 0; mt < 4; ++mt)
#pragma unroll
            for (int nt = 0; nt < 4; ++nt)
                acc[mt][nt] = __builtin_amdgcn_mfma_f32_16x16x32_bf16(
                    a[mt], b[nt], acc[mt][nt], 0, 0, 0);
    }

    // C/D layout: col = lane&15, row = (lane>>4)*4 + reg   [m89-verified]
#pragma unroll
    for (int mt = 0; mt < 4; ++mt) {
#pragma unroll
        for (int nt = 0; nt < 4; ++nt) {
            const int c = col0 + wn + nt * 16 + l15;
#pragma unroll
            for (int r = 0; r < 4; ++r) {
                const int row = row0 + wm + mt * 16 + quad * 4 + r;
                C[(size_t)row * N + c] = f2bf(acc[mt][nt][r]);
            }
        }
    }
}

// ---------------- CSR gather aggregation (bf16 features, pre-scaled rows) ----
template <int F, bool RELU, bool OUTF32>
__global__ __launch_bounds__(256) void k_gather(
    const int* __restrict__ row_start, const int* __restrict__ csr_src,
    const float* __restrict__ dinv, const unsigned short* __restrict__ h,
    const float* __restrict__ bias, unsigned short* __restrict__ ob,
    float* __restrict__ of, int N) {
    const int gid  = blockIdx.x * blockDim.x + threadIdx.x;
    const int node = gid >> 6;
    const int lane = gid & 63;
    if (node >= N) return;

    constexpr int EL = F / 64;           // 4 (F=256) or 2 (F=128)
    const float wd = dinv[node];
    const int jb = row_start[node];
    const int je = row_start[node + 1];
    const unsigned short* hl = h + (size_t)lane * EL;

    float acc[EL];
    {   // self-loop term (h already dinv-scaled)
        const unsigned short* hp = hl + (size_t)node * F;
        if (EL == 4) {
            const ushort4 v = *(const ushort4*)hp;
            acc[0] = bf2f(v.x); acc[1] = bf2f(v.y);
            acc[2] = bf2f(v.z); acc[3] = bf2f(v.w);
        } else {
            const ushort2 v = *(const ushort2*)hp;
            acc[0] = bf2f(v.x); acc[1] = bf2f(v.y);
        }
    }

    for (int j0 = jb; j0 < je; j0 += 64) {
        int jj = j0 + lane;
        if (jj >= je) jj = je - 1;
        const int myi = csr_src[jj];
        const int rem = je - j0;
        const int cnt = rem < 64 ? rem : 64;
        int i = 0;
        for (; i + 8 <= cnt; i += 8) {   // 8 independent row loads in flight
            int s[8];
#pragma unroll
            for (int u = 0; u < 8; ++u) s[u] = __shfl(myi, i + u);
            if (EL == 4) {
                ushort4 v[8];
#pragma unroll
                for (int u = 0; u < 8; ++u)
                    v[u] = *(const ushort4*)(hl + (size_t)s[u] * F);
#pragma unroll
                for (int u = 0; u < 8; ++u) {
                    acc[0] += bf2f(v[u].x); acc[1] += bf2f(v[u].y);
                    acc[2] += bf2f(v[u].z); acc[3] += bf2f(v[u].w);
                }
            } else {
                ushort2 v[8];
#pragma unroll
                for (int u = 0; u < 8; ++u)
                    v[u] = *(const ushort2*)(hl + (size_t)s[u] * F);
#pragma unroll
                for (int u = 0; u < 8; ++u) {
                    acc[0] += bf2f(v[u].x); acc[1] += bf2f(v[u].y);
                }
            }
        }
        for (; i + 4 <= cnt; i += 4) {
            const int s0 = __shfl(myi, i + 0);
            const int s1 = __shfl(myi, i + 1);
            const int s2 = __shfl(myi, i + 2);
            const int s3 = __shfl(myi, i + 3);
            if (EL == 4) {
                const ushort4 v0 = *(const ushort4*)(hl + (size_t)s0 * F);
                const ushort4 v1 = *(const ushort4*)(hl + (size_t)s1 * F);
                const ushort4 v2 = *(const ushort4*)(hl + (size_t)s2 * F);
                const ushort4 v3 = *(const ushort4*)(hl + (size_t)s3 * F);
                acc[0] += bf2f(v0.x) + bf2f(v1.x) + bf2f(v2.x) + bf2f(v3.x);
                acc[1] += bf2f(v0.y) + bf2f(v1.y) + bf2f(v2.y) + bf2f(v3.y);
                acc[2] += bf2f(v0.z) + bf2f(v1.z) + bf2f(v2.z) + bf2f(v3.z);
                acc[3] += bf2f(v0.w) + bf2f(v1.w) + bf2f(v2.w) + bf2f(v3.w);
            } else {
                const ushort2 v0 = *(const ushort2*)(hl + (size_t)s0 * F);
                const ushort2 v1 = *(const ushort2*)(hl + (size_t)s1 * F);
                const ushort2 v2 = *(const ushort2*)(hl + (size_t)s2 * F);
                const ushort2 v3 = *(const ushort2*)(hl + (size_t)s3 * F);
                acc[0] += bf2f(v0.x) + bf2f(v1.x) + bf2f(v2.x) + bf2f(v3.x);
                acc[1] += bf2f(v0.y) + bf2f(v1.y) + bf2f(v2.y) + bf2f(v3.y);
            }
        }
        for (; i < cnt; ++i) {
            const int s = __shfl(myi, i);
            const unsigned short* hp = hl + (size_t)s * F;
            if (EL == 4) {
                const ushort4 v = *(const ushort4*)hp;
                acc[0] += bf2f(v.x); acc[1] += bf2f(v.y);
                acc[2] += bf2f(v.z); acc[3] += bf2f(v.w);
            } else {
                const ushort2 v = *(const ushort2*)hp;
                acc[0] += bf2f(v.x); acc[1] += bf2f(v.y);
            }
        }
    }

#pragma unroll
    for (int i = 0; i < EL; ++i) {
        float v = fmaf(acc[i], wd, bias[lane * EL + i]);
        if (OUTF32) {
            of[(size_t)node * F + lane * EL + i] = v;
        } else {
            if (RELU) v = fmaxf(v, 0.f);
            ob[(size_t)node * F + lane * EL + i] = f2bf(v * wd);  // pre-scale for next layer
        }
    }
}

extern "C" void kernel_launch(void* const* d_in, const int* in_sizes, int n_in,
                              void* d_out, int out_size, void* d_ws, size_t ws_size,
                              hipStream_t stream) {
    const float* x   = (const float*)d_in[0];
    const int*   ei  = (const int*)d_in[1];
    const float* W1  = (const float*)d_in[2];
    const float* b1  = (const float*)d_in[3];
    const float* W2  = (const float*)d_in[4];
    const float* b2  = (const float*)d_in[5];
    float*       out = (float*)d_out;

    const int N = in_sizes[0] / NFEAT;           // 50000
    const int E = in_sizes[1] / 2;               // 800000
    const int Mp = ((N + 127) / 128) * 128;      // 50048
    const int* srcp = ei;
    const int* dstp = ei + E;
    const int CE = (E + P_CHUNKS - 1) / P_CHUNKS;   // 6250
    const int nRed = (N + 255) / 256;               // 196 (<=1024 for scan2)

    // workspace layout (256B aligned chunks)
    char* wsb = (char*)d_ws;
    auto take = [&](size_t bytes) {
        char* p = wsb;
        wsb += (bytes + 255) & ~(size_t)255;
        return p;
    };
    int*   degi      = (int*)take((size_t)N * 4);
    int*   row_start = (int*)take((size_t)(N + 1) * 4);
    int*   csr_src   = (int*)take((size_t)E * 4);
    int*   blocksums = (int*)take((size_t)1024 * 4);
    int*   blockoffs = (int*)take((size_t)1024 * 4);
    float* dinv      = (float*)take((size_t)N * 4);
    unsigned short* h2r = (unsigned short*)take((size_t)Mp * NH2 * 2);   // h2
    unsigned short* W1t = (unsigned short*)take((size_t)NH1 * NFEAT * 2);
    unsigned short* W2t = (unsigned short*)take((size_t)NH2 * NH1 * 2);
    // union region: hist (25.7 MB, dead before GEMM1) overlaps h + h1 (51.2 MB)
    const size_t hBytes    = (size_t)Mp * NH1 * 2;
    const size_t histBytes = (size_t)P_CHUNKS * NP * 4;
    char* big = take(histBytes > 2 * hBytes ? histBytes : 2 * hBytes);
    int*            hist = (int*)big;
    unsigned short* h    = (unsigned short*)big;
    unsigned short* h1   = (unsigned short*)(big + hBytes);
    unsigned short* h2   = h2r;

    // ABLATION (this round only): run the ENTIRE 9-dispatch pipeline twice.
    // Second pass recomputes identical values (all stages idempotent as a unit,
    // established R6/R7). Delta vs R5 == full warm pipeline (kernels + gaps);
    // 319.6 - delta == fixed per-iteration overhead no kernel change can touch.
    for (int rep = 0; rep < 2; ++rep) {
        {
            const int HB = P_CHUNKS * 2;                                    // 256
            const int CB = (NFEAT * NH1 + NH1 * NH2 + HPB - 1) / HPB;       // 160
            k_hist_cvtw<<<HB + CB, HPB, 0, stream>>>(dstp, hist, W1, W1t, W2, W2t,
                                                     E, CE, HB);
        }
        k_redscan1<<<nRed, 256, 0, stream>>>(hist, degi, dinv, blocksums, N);
        k_scan2<<<1, 1024, 0, stream>>>(blocksums, blockoffs, row_start, nRed, N);
        k_scan3off<<<nRed, 256, 0, stream>>>(degi, blockoffs, row_start, hist, N);
        k_place<<<P_CHUNKS * 2, HPB, 0, stream>>>(srcp, dstp, hist, csr_src, E, CE);

        gemm_x_fused<<<Mp / 128, 512, 0, stream>>>(x, dinv, W1t, h, N, NFEAT);
        {
            int total = N * 64;
            k_gather<NH1, true, false><<<(total + 255) / 256, 256, 0, stream>>>(
                row_start, csr_src, dinv, h, b1, h1, nullptr, N);
        }
        {
            dim3 g(NH2 / 128, Mp / 128);
            gemm_bf16<<<g, 256, 0, stream>>>(h1, W2t, h2, NH2, NH1);
        }
        {
            int total = N * 64;
            k_gather<NH2, false, true><<<(total + 255) / 256, 256, 0, stream>>>(
                row_start, csr_src, dinv, h2, b2, nullptr, out, N);
        }
    }
}

// Round 10
// 395.171 us; speedup vs baseline: 1.2177x; 1.2177x over previous
//
#include <hip/hip_runtime.h>
#include <cstdint>
#include <cstddef>

#define NFEAT 512
#define NH1   256
#define NH2   128

#define P_CHUNKS 128          // edge chunks for privatized histogram
#define HHALF    25088        // nodes per half (2*HHALF = 50176 >= N)
#define NP       (2 * HHALF)  // padded node count in hist rows
#define HPB      1024         // threads per hist/place block (16 waves)

typedef __attribute__((ext_vector_type(8))) short short8;
typedef __attribute__((ext_vector_type(4))) float float4v;

__device__ __forceinline__ unsigned short f2bf(float f) {
    unsigned int u = __float_as_uint(f);
    u += 0x7fffu + ((u >> 16) & 1u);   // round-to-nearest-even
    return (unsigned short)(u >> 16);
}
__device__ __forceinline__ float bf2f(unsigned short u) {
    return __uint_as_float(((unsigned int)u) << 16);
}

__device__ __forceinline__ void load_lds16(const void* g, void* l) {
    __builtin_amdgcn_global_load_lds(
        (const __attribute__((address_space(1))) void*)g,
        (__attribute__((address_space(3))) void*)l, 16, 0, 0);
}

// ---------------- CSR build: LDS-privatized counting sort ----------------
__global__ __launch_bounds__(HPB) void k_hist_cvtw(
    const int* __restrict__ dst, int* __restrict__ hist,
    const float* __restrict__ W1, unsigned short* __restrict__ W1t,
    const float* __restrict__ W2, unsigned short* __restrict__ W2t,
    int E, int CE, int HB) {
    __shared__ int lh[HHALF];
    if (blockIdx.x >= HB) {   // weight-conversion blocks (uniform branch)
        const int i = (blockIdx.x - HB) * HPB + (int)threadIdx.x;
        const int T1 = NFEAT * NH1;
        const int T2 = NH1 * NH2;
        if (i < T1) {
            const int k = i / NH1, n = i % NH1;
            W1t[(size_t)n * NFEAT + k] = f2bf(W1[i]);
        } else if (i < T1 + T2) {
            const int j = i - T1;
            const int k = j / NH2, n = j % NH2;
            W2t[(size_t)n * NH1 + k] = f2bf(W2[j]);
        }
        return;
    }
    const int c    = blockIdx.x >> 1;
    const int hf   = blockIdx.x & 1;
    const int base = hf * HHALF;
    for (int i = threadIdx.x; i < HHALF; i += HPB) lh[i] = 0;
    __syncthreads();
    const int lo = c * CE;
    const int hi = lo + CE < E ? lo + CE : E;
    for (int e = lo + (int)threadIdx.x; e < hi; e += HPB) {
        const int d = dst[e] - base;
        if ((unsigned)d < (unsigned)HHALF) atomicAdd(&lh[d], 1);
    }
    __syncthreads();
    int* outp = hist + (size_t)c * NP + base;
    for (int i = threadIdx.x; i < HHALF; i += HPB) outp[i] = lh[i];
}

// Fused: column-reduce hist -> degi, dinv ; block partial sums -> blocksums.
__global__ __launch_bounds__(256) void k_redscan1(
    const int* __restrict__ hist, int* __restrict__ degi,
    float* __restrict__ dinv, int* __restrict__ blocksums, int N) {
    __shared__ int red[256];
    const int t = threadIdx.x;
    const int d = blockIdx.x * 256 + t;
    int s = 0;
    if (d < N) {
#pragma unroll 8
        for (int c = 0; c < P_CHUNKS; ++c) s += hist[(size_t)c * NP + d];
        degi[d] = s;
        dinv[d] = rsqrtf((float)(s + 1));   // +1 = self-loop
    }
    red[t] = s;
    __syncthreads();
    for (int off = 128; off > 0; off >>= 1) {
        if (t < off) red[t] += red[t + off];
        __syncthreads();
    }
    if (t == 0) blocksums[blockIdx.x] = red[0];
}

__global__ __launch_bounds__(1024) void k_scan2(
    const int* __restrict__ blocksums, int* __restrict__ blockoffs,
    int* __restrict__ row_start, int nb, int N) {
    __shared__ int sm[1024];
    const int t = threadIdx.x;
    const int v = (t < nb) ? blocksums[t] : 0;
    sm[t] = v;
    __syncthreads();
    for (int off = 1; off < 1024; off <<= 1) {
        const int x = (t >= off) ? sm[t - off] : 0;
        __syncthreads();
        sm[t] += x;
        __syncthreads();
    }
    if (t < nb) blockoffs[t] = sm[t] - v;
    if (t == 1023) row_start[N] = sm[1023];
}

// Fused: final scan -> row_start[d], then in-place column exclusive scan of
// hist[c][d] into global base offsets.
__global__ __launch_bounds__(256) void k_scan3off(
    const int* __restrict__ degi, const int* __restrict__ blockoffs,
    int* __restrict__ row_start, int* __restrict__ hist, int N) {
    __shared__ int tsum[256];
    const int t = threadIdx.x;
    const int d = blockIdx.x * 256 + t;
    const int v = (d < N) ? degi[d] : 0;
    tsum[t] = v;
    __syncthreads();
    for (int off = 1; off < 256; off <<= 1) {
        const int x = (t >= off) ? tsum[t - off] : 0;
        __syncthreads();
        tsum[t] += x;
        __syncthreads();
    }
    if (d < N) {
        int run = blockoffs[blockIdx.x] + tsum[t] - v;   // exclusive prefix
        row_start[d] = run;
        for (int c = 0; c < P_CHUNKS; ++c) {
            int* p = &hist[(size_t)c * NP + d];
            const int tt = *p;
            *p = run;
            run += tt;
        }
    }
}

// Phase E: place edges. LDS cursor atomics only; plain scattered stores.
__global__ __launch_bounds__(HPB) void k_place(const int* __restrict__ src,
                                               const int* __restrict__ dst,
                                               const int* __restrict__ hist,
                                               int* __restrict__ csr_src, int E, int CE) {
    __shared__ int lcur[HHALF];
    const int c    = blockIdx.x >> 1;
    const int hf   = blockIdx.x & 1;
    const int base = hf * HHALF;
    const int* offp = hist + (size_t)c * NP + base;
    for (int i = threadIdx.x; i < HHALF; i += HPB) lcur[i] = offp[i];
    __syncthreads();
    const int lo = c * CE;
    const int hi = lo + CE < E ? lo + CE : E;
    for (int e = lo + (int)threadIdx.x; e < hi; e += HPB) {
        const int d = dst[e] - base;
        if ((unsigned)d < (unsigned)HHALF) {
            const int p = atomicAdd(&lcur[d], 1);   // LDS atomic (fast)
            csr_src[p] = src[e];
        }
    }
}

// ---------------- fused layer-1 GEMM: h = bf16((x*dinv) @ W1) ----------------
__global__ __launch_bounds__(512) void gemm_x_fused(
    const float* __restrict__ x, const float* __restrict__ dinv,
    const unsigned short* __restrict__ Bt, unsigned short* __restrict__ C,
    int Nrows, int K) {
    __shared__ unsigned short As[128 * 32];   //  8 KB
    __shared__ unsigned short Bs[256 * 32];   // 16 KB
    const int t    = threadIdx.x;
    const int wave = t >> 6, lane = t & 63;
    const int row0 = blockIdx.x * 128;
    const int quad = lane >> 4, l15 = lane & 15;
    const int wm = (wave >> 2) * 64;          // 0 / 64
    const int wn = (wave & 3) * 64;           // 0 / 64 / 128 / 192

    const int arow = t >> 2;
    const int ak   = (t & 3) * 8;
    const int gr   = (row0 + arow < Nrows) ? row0 + arow : Nrows - 1;  // clamp pad rows
    const float wd = dinv[gr];
    const float* gx = x + (size_t)gr * K + ak;
    unsigned short* lA = &As[arow * 32 + ak];                 // byte off = t*16 (linear)

    const int brow = t >> 2;                  // 0..127 (seg2: +128)
    const int bk   = (t & 3) * 8;
    const unsigned short* gB0 = Bt + (size_t)brow * K + bk;
    const unsigned short* gB1 = Bt + (size_t)(128 + brow) * K + bk;
    unsigned short* lB0 = &Bs[wave * 512];            // wave-uniform base + lane*16
    unsigned short* lB1 = &Bs[128 * 32 + wave * 512];

    float4v acc[4][4] = {};

    for (int k0 = 0; k0 < K; k0 += 32) {
        __syncthreads();
        load_lds16(gB0 + k0, lB0);
        load_lds16(gB1 + k0, lB1);
        const float4 v0 = *(const float4*)(gx + k0);
        const float4 v1 = *(const float4*)(gx + k0 + 4);
        short8 o;
        o[0] = (short)f2bf(v0.x * wd); o[1] = (short)f2bf(v0.y * wd);
        o[2] = (short)f2bf(v0.z * wd); o[3] = (short)f2bf(v0.w * wd);
        o[4] = (short)f2bf(v1.x * wd); o[5] = (short)f2bf(v1.y * wd);
        o[6] = (short)f2bf(v1.z * wd); o[7] = (short)f2bf(v1.w * wd);
        *(short8*)lA = o;                                   // 16B ds_write
        __syncthreads();

        short8 a[4], b[4];
#pragma unroll
        for (int i = 0; i < 4; ++i) {
            a[i] = *(const short8*)&As[(wm + i * 16 + l15) * 32 + quad * 8];
            b[i] = *(const short8*)&Bs[(wn + i * 16 + l15) * 32 + quad * 8];
        }
#pragma unroll
        for (int mt = 0; mt < 4; ++mt)
#pragma unroll
            for (int nt = 0; nt < 4; ++nt)
                acc[mt][nt] = __builtin_amdgcn_mfma_f32_16x16x32_bf16(
                    a[mt], b[nt], acc[mt][nt], 0, 0, 0);
    }

    // C/D layout: col = lane&15, row = (lane>>4)*4 + reg   [m89-verified]
#pragma unroll
    for (int mt = 0; mt < 4; ++mt) {
#pragma unroll
        for (int nt = 0; nt < 4; ++nt) {
            const int c = wn + nt * 16 + l15;
#pragma unroll
            for (int r = 0; r < 4; ++r) {
                const int row = row0 + wm + mt * 16 + quad * 4 + r;
                C[(size_t)row * NH1 + c] = f2bf(acc[mt][nt][r]);
            }
        }
    }
}

// ---------------- bf16 MFMA GEMM (layer 2) ----------------
__global__ __launch_bounds__(256) void gemm_bf16(
    const unsigned short* __restrict__ A, const unsigned short* __restrict__ Bt,
    unsigned short* __restrict__ C, int N, int K) {
    __shared__ unsigned short As[128 * 32];
    __shared__ unsigned short Bs[128 * 32];
    const int t    = threadIdx.x;
    const int wave = t >> 6, lane = t & 63;
    const int row0 = blockIdx.y * 128, col0 = blockIdx.x * 128;
    const int wm = (wave >> 1) * 64, wn = (wave & 1) * 64;
    const int sr = lane >> 2;
    const int sk = (lane & 3) * 8;
    const int quad = lane >> 4, l15 = lane & 15;

    const int ca = wave * 2;
    const unsigned short* gA0 = A  + (size_t)(row0 + ca * 16 + sr) * K + sk;
    const unsigned short* gA1 = gA0 + (size_t)16 * K;
    const unsigned short* gB0 = Bt + (size_t)(col0 + ca * 16 + sr) * K + sk;
    const unsigned short* gB1 = gB0 + (size_t)16 * K;
    unsigned short* lA0 = &As[ca * 512];
    unsigned short* lA1 = &As[(ca + 1) * 512];
    unsigned short* lB0 = &Bs[ca * 512];
    unsigned short* lB1 = &Bs[(ca + 1) * 512];

    float4v acc[4][4] = {};

    for (int k0 = 0; k0 < K; k0 += 32) {
        __syncthreads();
        load_lds16(gA0 + k0, lA0);
        load_lds16(gA1 + k0, lA1);
        load_lds16(gB0 + k0, lB0);
        load_lds16(gB1 + k0, lB1);
        __syncthreads();

        short8 a[4], b[4];
#pragma unroll
        for (int i = 0; i < 4; ++i) {
            a[i] = *(const short8*)&As[(wm + i * 16 + l15) * 32 + quad * 8];
            b[i] = *(const short8*)&Bs[(wn + i * 16 + l15) * 32 + quad * 8];
        }
#pragma unroll
        for (int mt = 0; mt < 4; ++mt)
#pragma unroll
            for (int nt = 0; nt < 4; ++nt)
                acc[mt][nt] = __builtin_amdgcn_mfma_f32_16x16x32_bf16(
                    a[mt], b[nt], acc[mt][nt], 0, 0, 0);
    }

    // C/D layout: col = lane&15, row = (lane>>4)*4 + reg   [m89-verified]
#pragma unroll
    for (int mt = 0; mt < 4; ++mt) {
#pragma unroll
        for (int nt = 0; nt < 4; ++nt) {
            const int c = col0 + wn + nt * 16 + l15;
#pragma unroll
            for (int r = 0; r < 4; ++r) {
                const int row = row0 + wm + mt * 16 + quad * 4 + r;
                C[(size_t)row * N + c] = f2bf(acc[mt][nt][r]);
            }
        }
    }
}

// ------- XCD-pinned feature-sliced CSR gather -------
// Slice = 32 features (3.2 MB over all nodes -> fits one XCD's 4 MB L2).
// slice = blockIdx.x % NSL: round-robin block->XCD dispatch pins each slice
// to (a fixed set of) XCD(s), so slice rows are served from the local L2.
// Work unit: half-wave (32 lanes = 32 feats) per node; __shfl width=32.
template <int F, int NSL, int LSH, bool RELU, bool OUTF32>
__global__ __launch_bounds__(256) void k_gather_x(
    const int* __restrict__ row_start, const int* __restrict__ csr_src,
    const float* __restrict__ dinv, const unsigned short* __restrict__ h,
    const float* __restrict__ bias, unsigned short* __restrict__ ob,
    float* __restrict__ of, int N) {
    const int slice = blockIdx.x & (NSL - 1);
    const int ng    = blockIdx.x >> LSH;
    const int hw    = threadIdx.x >> 5;        // half-wave id 0..7
    const int l31   = threadIdx.x & 31;
    const int node  = ng * 8 + hw;
    if (node >= N) return;
    const int feat  = slice * 32 + l31;

    const float wd = dinv[node];
    const int jb = row_start[node];
    const int je = row_start[node + 1];
    const unsigned short* hf = h + feat;

    float acc = bf2f(hf[(size_t)node * F]);    // self-loop (h pre-scaled)

    for (int j0 = jb; j0 < je; j0 += 32) {
        int jj = j0 + l31;
        if (jj >= je) jj = je - 1;
        const int myi = csr_src[jj];
        const int rem = je - j0;
        const int cnt = rem < 32 ? rem : 32;
        int i = 0;
        for (; i + 4 <= cnt; i += 4) {         // 4 loads in flight
            const int s0 = __shfl(myi, i + 0, 32);
            const int s1 = __shfl(myi, i + 1, 32);
            const int s2 = __shfl(myi, i + 2, 32);
            const int s3 = __shfl(myi, i + 3, 32);
            const float v0 = bf2f(hf[(size_t)s0 * F]);
            const float v1 = bf2f(hf[(size_t)s1 * F]);
            const float v2 = bf2f(hf[(size_t)s2 * F]);
            const float v3 = bf2f(hf[(size_t)s3 * F]);
            acc += v0 + v1 + v2 + v3;
        }
        for (; i < cnt; ++i) {
            const int s = __shfl(myi, i, 32);
            acc += bf2f(hf[(size_t)s * F]);
        }
    }

    float v = fmaf(acc, wd, bias[feat]);
    if (OUTF32) {
        of[(size_t)node * F + feat] = v;
    } else {
        if (RELU) v = fmaxf(v, 0.f);
        ob[(size_t)node * F + feat] = f2bf(v * wd);   // pre-scale for next layer
    }
}

extern "C" void kernel_launch(void* const* d_in, const int* in_sizes, int n_in,
                              void* d_out, int out_size, void* d_ws, size_t ws_size,
                              hipStream_t stream) {
    const float* x   = (const float*)d_in[0];
    const int*   ei  = (const int*)d_in[1];
    const float* W1  = (const float*)d_in[2];
    const float* b1  = (const float*)d_in[3];
    const float* W2  = (const float*)d_in[4];
    const float* b2  = (const float*)d_in[5];
    float*       out = (float*)d_out;

    const int N = in_sizes[0] / NFEAT;           // 50000
    const int E = in_sizes[1] / 2;               // 800000
    const int Mp = ((N + 127) / 128) * 128;      // 50048
    const int* srcp = ei;
    const int* dstp = ei + E;
    const int CE = (E + P_CHUNKS - 1) / P_CHUNKS;   // 6250
    const int nRed = (N + 255) / 256;               // 196 (<=1024 for scan2)
    const int nodeGroups = (N + 7) / 8;             // 6250

    // workspace layout (256B aligned chunks)
    char* wsb = (char*)d_ws;
    auto take = [&](size_t bytes) {
        char* p = wsb;
        wsb += (bytes + 255) & ~(size_t)255;
        return p;
    };
    int*   degi      = (int*)take((size_t)N * 4);
    int*   row_start = (int*)take((size_t)(N + 1) * 4);
    int*   csr_src   = (int*)take((size_t)E * 4);
    int*   blocksums = (int*)take((size_t)1024 * 4);
    int*   blockoffs = (int*)take((size_t)1024 * 4);
    float* dinv      = (float*)take((size_t)N * 4);
    unsigned short* h2r = (unsigned short*)take((size_t)Mp * NH2 * 2);   // h2
    unsigned short* W1t = (unsigned short*)take((size_t)NH1 * NFEAT * 2);
    unsigned short* W2t = (unsigned short*)take((size_t)NH2 * NH1 * 2);
    // union region: hist (25.7 MB, dead before GEMM1) overlaps h + h1 (51.2 MB)
    const size_t hBytes    = (size_t)Mp * NH1 * 2;
    const size_t histBytes = (size_t)P_CHUNKS * NP * 4;
    char* big = take(histBytes > 2 * hBytes ? histBytes : 2 * hBytes);
    int*            hist = (int*)big;
    unsigned short* h    = (unsigned short*)big;
    unsigned short* h1   = (unsigned short*)(big + hBytes);
    unsigned short* h2   = h2r;

    // ---- CSR build (atomic-free) + dinv + weight cvt: 5 dispatches ----
    {
        const int HB = P_CHUNKS * 2;                                    // 256
        const int CB = (NFEAT * NH1 + NH1 * NH2 + HPB - 1) / HPB;       // 160
        k_hist_cvtw<<<HB + CB, HPB, 0, stream>>>(dstp, hist, W1, W1t, W2, W2t,
                                                 E, CE, HB);
    }
    k_redscan1<<<nRed, 256, 0, stream>>>(hist, degi, dinv, blocksums, N);
    k_scan2<<<1, 1024, 0, stream>>>(blocksums, blockoffs, row_start, nRed, N);
    k_scan3off<<<nRed, 256, 0, stream>>>(degi, blockoffs, row_start, hist, N);
    k_place<<<P_CHUNKS * 2, HPB, 0, stream>>>(srcp, dstp, hist, csr_src, E, CE);

    // ---- layer 1: h = (x*dinv)@W1 fused (bf16) ; h1 = relu(...)*dinv (bf16) ----
    gemm_x_fused<<<Mp / 128, 512, 0, stream>>>(x, dinv, W1t, h, N, NFEAT);
    // 8 slices x 32 feats; slice = blockIdx % 8 -> one slice per XCD L2
    k_gather_x<NH1, 8, 3, true, false><<<nodeGroups * 8, 256, 0, stream>>>(
        row_start, csr_src, dinv, h, b1, h1, nullptr, N);

    // ---- layer 2: h2 = h1s@W2 (bf16) ; out = gather + b2 (fp32) ----
    {
        dim3 g(NH2 / 128, Mp / 128);
        gemm_bf16<<<g, 256, 0, stream>>>(h1, W2t, h2, NH2, NH1);
    }
    // 4 slices x 32 feats; slice = blockIdx % 4 -> slice pinned to 2 XCDs
    k_gather_x<NH2, 4, 2, false, true><<<nodeGroups * 4, 256, 0, stream>>>(
        row_start, csr_src, dinv, h2, b2, nullptr, out, N);
}

// Round 11
// 314.778 us; speedup vs baseline: 1.5286x; 1.2554x over previous
//
#include <hip/hip_runtime.h>
#include <cstdint>
#include <cstddef>

#define NFEAT 512
#define NH1   256
#define NH2   128

#define P_CHUNKS 64           // edge chunks for privatized histogram
#define HQ       12544        // nodes per quarter (4*HQ = 50176 >= N)
#define NP       (4 * HQ)     // padded node count in hist rows
#define HPB      1024         // threads per hist/place block (16 waves)

typedef __attribute__((ext_vector_type(8))) short short8;
typedef __attribute__((ext_vector_type(4))) float float4v;

__device__ __forceinline__ unsigned short f2bf(float f) {
    unsigned int u = __float_as_uint(f);
    u += 0x7fffu + ((u >> 16) & 1u);   // round-to-nearest-even
    return (unsigned short)(u >> 16);
}
__device__ __forceinline__ float bf2f(unsigned short u) {
    return __uint_as_float(((unsigned int)u) << 16);
}

__device__ __forceinline__ void load_lds16(const void* g, void* l) {
    __builtin_amdgcn_global_load_lds(
        (const __attribute__((address_space(1))) void*)g,
        (__attribute__((address_space(3))) void*)l, 16, 0, 0);
}

// ---------------- CSR build: LDS-privatized counting sort ----------------
// Phase A: per-(chunk,quarter) histogram in LDS (50 KB -> grid 256 covers all
// CUs) + weight conversion piggybacked as extra blocks.
__global__ __launch_bounds__(HPB) void k_hist_cvtw(
    const int* __restrict__ dst, int* __restrict__ hist,
    const float* __restrict__ W1, unsigned short* __restrict__ W1t,
    const float* __restrict__ W2, unsigned short* __restrict__ W2t,
    int E, int CE, int HB) {
    __shared__ int lh[HQ];
    if (blockIdx.x >= HB) {   // weight-conversion blocks (uniform branch)
        const int i = (blockIdx.x - HB) * HPB + (int)threadIdx.x;
        const int T1 = NFEAT * NH1;
        const int T2 = NH1 * NH2;
        if (i < T1) {
            const int k = i / NH1, n = i % NH1;
            W1t[(size_t)n * NFEAT + k] = f2bf(W1[i]);
        } else if (i < T1 + T2) {
            const int j = i - T1;
            const int k = j / NH2, n = j % NH2;
            W2t[(size_t)n * NH1 + k] = f2bf(W2[j]);
        }
        return;
    }
    const int c    = blockIdx.x >> 2;
    const int q    = blockIdx.x & 3;
    const int base = q * HQ;
    for (int i = threadIdx.x; i < HQ; i += HPB) lh[i] = 0;
    __syncthreads();
    const int lo = c * CE;
    const int hi = lo + CE < E ? lo + CE : E;
    for (int e = lo + (int)threadIdx.x; e < hi; e += HPB) {
        const int d = dst[e] - base;
        if ((unsigned)d < (unsigned)HQ) atomicAdd(&lh[d], 1);
    }
    __syncthreads();
    int* outp = hist + (size_t)c * NP + base;
    for (int i = threadIdx.x; i < HQ; i += HPB) outp[i] = lh[i];
}

// Fused: column-reduce hist -> degi, dinv ; block partial sums -> blocksums.
__global__ __launch_bounds__(256) void k_redscan1(
    const int* __restrict__ hist, int* __restrict__ degi,
    float* __restrict__ dinv, int* __restrict__ blocksums, int N) {
    __shared__ int red[256];
    const int t = threadIdx.x;
    const int d = blockIdx.x * 256 + t;
    int s = 0;
    if (d < N) {
#pragma unroll 8
        for (int c = 0; c < P_CHUNKS; ++c) s += hist[(size_t)c * NP + d];
        degi[d] = s;
        dinv[d] = rsqrtf((float)(s + 1));   // +1 = self-loop
    }
    red[t] = s;
    __syncthreads();
    for (int off = 128; off > 0; off >>= 1) {
        if (t < off) red[t] += red[t + off];
        __syncthreads();
    }
    if (t == 0) blocksums[blockIdx.x] = red[0];
}

__global__ __launch_bounds__(1024) void k_scan2(
    const int* __restrict__ blocksums, int* __restrict__ blockoffs,
    int* __restrict__ row_start, int nb, int N) {
    __shared__ int sm[1024];
    const int t = threadIdx.x;
    const int v = (t < nb) ? blocksums[t] : 0;
    sm[t] = v;
    __syncthreads();
    for (int off = 1; off < 1024; off <<= 1) {
        const int x = (t >= off) ? sm[t - off] : 0;
        __syncthreads();
        sm[t] += x;
        __syncthreads();
    }
    if (t < nb) blockoffs[t] = sm[t] - v;
    if (t == 1023) row_start[N] = sm[1023];
}

// Fused: final scan -> row_start[d], then in-place column exclusive scan of
// hist[c][d] into global base offsets.
__global__ __launch_bounds__(256) void k_scan3off(
    const int* __restrict__ degi, const int* __restrict__ blockoffs,
    int* __restrict__ row_start, int* __restrict__ hist, int N) {
    __shared__ int tsum[256];
    const int t = threadIdx.x;
    const int d = blockIdx.x * 256 + t;
    const int v = (d < N) ? degi[d] : 0;
    tsum[t] = v;
    __syncthreads();
    for (int off = 1; off < 256; off <<= 1) {
        const int x = (t >= off) ? tsum[t - off] : 0;
        __syncthreads();
        tsum[t] += x;
        __syncthreads();
    }
    if (d < N) {
        int run = blockoffs[blockIdx.x] + tsum[t] - v;   // exclusive prefix
        row_start[d] = run;
        for (int c = 0; c < P_CHUNKS; ++c) {
            int* p = &hist[(size_t)c * NP + d];
            const int tt = *p;
            *p = run;
            run += tt;
        }
    }
}

// Phase E: place edges. LDS cursor atomics only; plain scattered stores.
__global__ __launch_bounds__(HPB) void k_place(const int* __restrict__ src,
                                               const int* __restrict__ dst,
                                               const int* __restrict__ hist,
                                               int* __restrict__ csr_src, int E, int CE) {
    __shared__ int lcur[HQ];
    const int c    = blockIdx.x >> 2;
    const int q    = blockIdx.x & 3;
    const int base = q * HQ;
    const int* offp = hist + (size_t)c * NP + base;
    for (int i = threadIdx.x; i < HQ; i += HPB) lcur[i] = offp[i];
    __syncthreads();
    const int lo = c * CE;
    const int hi = lo + CE < E ? lo + CE : E;
    for (int e = lo + (int)threadIdx.x; e < hi; e += HPB) {
        const int d = dst[e] - base;
        if ((unsigned)d < (unsigned)HQ) {
            const int p = atomicAdd(&lcur[d], 1);   // LDS atomic (fast)
            csr_src[p] = src[e];
        }
    }
}

// ---------------- fused layer-1 GEMM: h = bf16((x*dinv) @ W1) ----------------
__global__ __launch_bounds__(512) void gemm_x_fused(
    const float* __restrict__ x, const float* __restrict__ dinv,
    const unsigned short* __restrict__ Bt, unsigned short* __restrict__ C,
    int Nrows, int K) {
    __shared__ unsigned short As[128 * 32];   //  8 KB
    __shared__ unsigned short Bs[256 * 32];   // 16 KB
    const int t    = threadIdx.x;
    const int wave = t >> 6, lane = t & 63;
    const int row0 = blockIdx.x * 128;
    const int quad = lane >> 4, l15 = lane & 15;
    const int wm = (wave >> 2) * 64;          // 0 / 64
    const int wn = (wave & 3) * 64;           // 0 / 64 / 128 / 192

    const int arow = t >> 2;
    const int ak   = (t & 3) * 8;
    const int gr   = (row0 + arow < Nrows) ? row0 + arow : Nrows - 1;  // clamp pad rows
    const float wd = dinv[gr];
    const float* gx = x + (size_t)gr * K + ak;
    unsigned short* lA = &As[arow * 32 + ak];                 // byte off = t*16 (linear)

    const int brow = t >> 2;                  // 0..127 (seg2: +128)
    const int bk   = (t & 3) * 8;
    const unsigned short* gB0 = Bt + (size_t)brow * K + bk;
    const unsigned short* gB1 = Bt + (size_t)(128 + brow) * K + bk;
    unsigned short* lB0 = &Bs[wave * 512];            // wave-uniform base + lane*16
    unsigned short* lB1 = &Bs[128 * 32 + wave * 512];

    float4v acc[4][4] = {};

    for (int k0 = 0; k0 < K; k0 += 32) {
        __syncthreads();
        load_lds16(gB0 + k0, lB0);
        load_lds16(gB1 + k0, lB1);
        const float4 v0 = *(const float4*)(gx + k0);
        const float4 v1 = *(const float4*)(gx + k0 + 4);
        short8 o;
        o[0] = (short)f2bf(v0.x * wd); o[1] = (short)f2bf(v0.y * wd);
        o[2] = (short)f2bf(v0.z * wd); o[3] = (short)f2bf(v0.w * wd);
        o[4] = (short)f2bf(v1.x * wd); o[5] = (short)f2bf(v1.y * wd);
        o[6] = (short)f2bf(v1.z * wd); o[7] = (short)f2bf(v1.w * wd);
        *(short8*)lA = o;                                   // 16B ds_write
        __syncthreads();

        short8 a[4], b[4];
#pragma unroll
        for (int i = 0; i < 4; ++i) {
            a[i] = *(const short8*)&As[(wm + i * 16 + l15) * 32 + quad * 8];
            b[i] = *(const short8*)&Bs[(wn + i * 16 + l15) * 32 + quad * 8];
        }
#pragma unroll
        for (int mt = 0; mt < 4; ++mt)
#pragma unroll
            for (int nt = 0; nt < 4; ++nt)
                acc[mt][nt] = __builtin_amdgcn_mfma_f32_16x16x32_bf16(
                    a[mt], b[nt], acc[mt][nt], 0, 0, 0);
    }

    // C/D layout: col = lane&15, row = (lane>>4)*4 + reg   [m89-verified]
#pragma unroll
    for (int mt = 0; mt < 4; ++mt) {
#pragma unroll
        for (int nt = 0; nt < 4; ++nt) {
            const int c = wn + nt * 16 + l15;
#pragma unroll
            for (int r = 0; r < 4; ++r) {
                const int row = row0 + wm + mt * 16 + quad * 4 + r;
                C[(size_t)row * NH1 + c] = f2bf(acc[mt][nt][r]);
            }
        }
    }
}

// ---------------- bf16 MFMA GEMM (layer 2) ----------------
__global__ __launch_bounds__(256) void gemm_bf16(
    const unsigned short* __restrict__ A, const unsigned short* __restrict__ Bt,
    unsigned short* __restrict__ C, int N, int K) {
    __shared__ unsigned short As[128 * 32];
    __shared__ unsigned short Bs[128 * 32];
    const int t    = threadIdx.x;
    const int wave = t >> 6, lane = t & 63;
    const int row0 = blockIdx.y * 128, col0 = blockIdx.x * 128;
    const int wm = (wave >> 1) * 64, wn = (wave & 1) * 64;
    const int sr = lane >> 2;
    const int sk = (lane & 3) * 8;
    const int quad = lane >> 4, l15 = lane & 15;

    const int ca = wave * 2;
    const unsigned short* gA0 = A  + (size_t)(row0 + ca * 16 + sr) * K + sk;
    const unsigned short* gA1 = gA0 + (size_t)16 * K;
    const unsigned short* gB0 = Bt + (size_t)(col0 + ca * 16 + sr) * K + sk;
    const unsigned short* gB1 = gB0 + (size_t)16 * K;
    unsigned short* lA0 = &As[ca * 512];
    unsigned short* lA1 = &As[(ca + 1) * 512];
    unsigned short* lB0 = &Bs[ca * 512];
    unsigned short* lB1 = &Bs[(ca + 1) * 512];

    float4v acc[4][4] = {};

    for (int k0 = 0; k0 < K; k0 += 32) {
        __syncthreads();
        load_lds16(gA0 + k0, lA0);
        load_lds16(gA1 + k0, lA1);
        load_lds16(gB0 + k0, lB0);
        load_lds16(gB1 + k0, lB1);
        __syncthreads();

        short8 a[4], b[4];
#pragma unroll
        for (int i = 0; i < 4; ++i) {
            a[i] = *(const short8*)&As[(wm + i * 16 + l15) * 32 + quad * 8];
            b[i] = *(const short8*)&Bs[(wn + i * 16 + l15) * 32 + quad * 8];
        }
#pragma unroll
        for (int mt = 0; mt < 4; ++mt)
#pragma unroll
            for (int nt = 0; nt < 4; ++nt)
                acc[mt][nt] = __builtin_amdgcn_mfma_f32_16x16x32_bf16(
                    a[mt], b[nt], acc[mt][nt], 0, 0, 0);
    }

    // C/D layout: col = lane&15, row = (lane>>4)*4 + reg   [m89-verified]
#pragma unroll
    for (int mt = 0; mt < 4; ++mt) {
#pragma unroll
        for (int nt = 0; nt < 4; ++nt) {
            const int c = col0 + wn + nt * 16 + l15;
#pragma unroll
            for (int r = 0; r < 4; ++r) {
                const int row = row0 + wm + mt * 16 + quad * 4 + r;
                C[(size_t)row * N + c] = f2bf(acc[mt][nt][r]);
            }
        }
    }
}

// ---------------- CSR gather aggregation (bf16 features, pre-scaled rows) ----
// Full-row per wave (R5 form): 615 MB combined at ~7.4 TB/s effective — at the
// L3-fabric roofline (R5 pipeline-deepening null; R10 slice experiment regressed).
template <int F, bool RELU, bool OUTF32>
__global__ __launch_bounds__(256) void k_gather(
    const int* __restrict__ row_start, const int* __restrict__ csr_src,
    const float* __restrict__ dinv, const unsigned short* __restrict__ h,
    const float* __restrict__ bias, unsigned short* __restrict__ ob,
    float* __restrict__ of, int N) {
    const int gid  = blockIdx.x * blockDim.x + threadIdx.x;
    const int node = gid >> 6;
    const int lane = gid & 63;
    if (node >= N) return;

    constexpr int EL = F / 64;           // 4 (F=256) or 2 (F=128)
    const float wd = dinv[node];
    const int jb = row_start[node];
    const int je = row_start[node + 1];
    const unsigned short* hl = h + (size_t)lane * EL;

    float acc[EL];
    {   // self-loop term (h already dinv-scaled)
        const unsigned short* hp = hl + (size_t)node * F;
        if (EL == 4) {
            const ushort4 v = *(const ushort4*)hp;
            acc[0] = bf2f(v.x); acc[1] = bf2f(v.y);
            acc[2] = bf2f(v.z); acc[3] = bf2f(v.w);
        } else {
            const ushort2 v = *(const ushort2*)hp;
            acc[0] = bf2f(v.x); acc[1] = bf2f(v.y);
        }
    }

    for (int j0 = jb; j0 < je; j0 += 64) {
        int jj = j0 + lane;
        if (jj >= je) jj = je - 1;
        const int myi = csr_src[jj];
        const int rem = je - j0;
        const int cnt = rem < 64 ? rem : 64;
        int i = 0;
        for (; i + 8 <= cnt; i += 8) {   // 8 independent row loads in flight
            int s[8];
#pragma unroll
            for (int u = 0; u < 8; ++u) s[u] = __shfl(myi, i + u);
            if (EL == 4) {
                ushort4 v[8];
#pragma unroll
                for (int u = 0; u < 8; ++u)
                    v[u] = *(const ushort4*)(hl + (size_t)s[u] * F);
#pragma unroll
                for (int u = 0; u < 8; ++u) {
                    acc[0] += bf2f(v[u].x); acc[1] += bf2f(v[u].y);
                    acc[2] += bf2f(v[u].z); acc[3] += bf2f(v[u].w);
                }
            } else {
                ushort2 v[8];
#pragma unroll
                for (int u = 0; u < 8; ++u)
                    v[u] = *(const ushort2*)(hl + (size_t)s[u] * F);
#pragma unroll
                for (int u = 0; u < 8; ++u) {
                    acc[0] += bf2f(v[u].x); acc[1] += bf2f(v[u].y);
                }
            }
        }
        for (; i + 4 <= cnt; i += 4) {
            const int s0 = __shfl(myi, i + 0);
            const int s1 = __shfl(myi, i + 1);
            const int s2 = __shfl(myi, i + 2);
            const int s3 = __shfl(myi, i + 3);
            if (EL == 4) {
                const ushort4 v0 = *(const ushort4*)(hl + (size_t)s0 * F);
                const ushort4 v1 = *(const ushort4*)(hl + (size_t)s1 * F);
                const ushort4 v2 = *(const ushort4*)(hl + (size_t)s2 * F);
                const ushort4 v3 = *(const ushort4*)(hl + (size_t)s3 * F);
                acc[0] += bf2f(v0.x) + bf2f(v1.x) + bf2f(v2.x) + bf2f(v3.x);
                acc[1] += bf2f(v0.y) + bf2f(v1.y) + bf2f(v2.y) + bf2f(v3.y);
                acc[2] += bf2f(v0.z) + bf2f(v1.z) + bf2f(v2.z) + bf2f(v3.z);
                acc[3] += bf2f(v0.w) + bf2f(v1.w) + bf2f(v2.w) + bf2f(v3.w);
            } else {
                const ushort2 v0 = *(const ushort2*)(hl + (size_t)s0 * F);
                const ushort2 v1 = *(const ushort2*)(hl + (size_t)s1 * F);
                const ushort2 v2 = *(const ushort2*)(hl + (size_t)s2 * F);
                const ushort2 v3 = *(const ushort2*)(hl + (size_t)s3 * F);
                acc[0] += bf2f(v0.x) + bf2f(v1.x) + bf2f(v2.x) + bf2f(v3.x);
                acc[1] += bf2f(v0.y) + bf2f(v1.y) + bf2f(v2.y) + bf2f(v3.y);
            }
        }
        for (; i < cnt; ++i) {
            const int s = __shfl(myi, i);
            const unsigned short* hp = hl + (size_t)s * F;
            if (EL == 4) {
                const ushort4 v = *(const ushort4*)hp;
                acc[0] += bf2f(v.x); acc[1] += bf2f(v.y);
                acc[2] += bf2f(v.z); acc[3] += bf2f(v.w);
            } else {
                const ushort2 v = *(const ushort2*)hp;
                acc[0] += bf2f(v.x); acc[1] += bf2f(v.y);
            }
        }
    }

#pragma unroll
    for (int i = 0; i < EL; ++i) {
        float v = fmaf(acc[i], wd, bias[lane * EL + i]);
        if (OUTF32) {
            of[(size_t)node * F + lane * EL + i] = v;
        } else {
            if (RELU) v = fmaxf(v, 0.f);
            ob[(size_t)node * F + lane * EL + i] = f2bf(v * wd);  // pre-scale for next layer
        }
    }
}

extern "C" void kernel_launch(void* const* d_in, const int* in_sizes, int n_in,
                              void* d_out, int out_size, void* d_ws, size_t ws_size,
                              hipStream_t stream) {
    const float* x   = (const float*)d_in[0];
    const int*   ei  = (const int*)d_in[1];
    const float* W1  = (const float*)d_in[2];
    const float* b1  = (const float*)d_in[3];
    const float* W2  = (const float*)d_in[4];
    const float* b2  = (const float*)d_in[5];
    float*       out = (float*)d_out;

    const int N = in_sizes[0] / NFEAT;           // 50000
    const int E = in_sizes[1] / 2;               // 800000
    const int Mp = ((N + 127) / 128) * 128;      // 50048
    const int* srcp = ei;
    const int* dstp = ei + E;
    const int CE = (E + P_CHUNKS - 1) / P_CHUNKS;   // 12500
    const int nRed = (N + 255) / 256;               // 196 (<=1024 for scan2)

    // workspace layout (256B aligned chunks)
    char* wsb = (char*)d_ws;
    auto take = [&](size_t bytes) {
        char* p = wsb;
        wsb += (bytes + 255) & ~(size_t)255;
        return p;
    };
    int*   degi      = (int*)take((size_t)N * 4);
    int*   row_start = (int*)take((size_t)(N + 1) * 4);
    int*   csr_src   = (int*)take((size_t)E * 4);
    int*   blocksums = (int*)take((size_t)1024 * 4);
    int*   blockoffs = (int*)take((size_t)1024 * 4);
    float* dinv      = (float*)take((size_t)N * 4);
    unsigned short* h2r = (unsigned short*)take((size_t)Mp * NH2 * 2);   // h2
    unsigned short* W1t = (unsigned short*)take((size_t)NH1 * NFEAT * 2);
    unsigned short* W2t = (unsigned short*)take((size_t)NH2 * NH1 * 2);
    // union region: hist (12.9 MB, dead before GEMM1) overlaps h + h1 (51.2 MB)
    const size_t hBytes    = (size_t)Mp * NH1 * 2;
    const size_t histBytes = (size_t)P_CHUNKS * NP * 4;
    char* big = take(histBytes > 2 * hBytes ? histBytes : 2 * hBytes);
    int*            hist = (int*)big;
    unsigned short* h    = (unsigned short*)big;
    unsigned short* h1   = (unsigned short*)(big + hBytes);
    unsigned short* h2   = h2r;

    // ---- CSR build (atomic-free) + dinv + weight cvt: 5 dispatches ----
    {
        const int HB = P_CHUNKS * 4;                                    // 256
        const int CB = (NFEAT * NH1 + NH1 * NH2 + HPB - 1) / HPB;       // 160
        k_hist_cvtw<<<HB + CB, HPB, 0, stream>>>(dstp, hist, W1, W1t, W2, W2t,
                                                 E, CE, HB);
    }
    k_redscan1<<<nRed, 256, 0, stream>>>(hist, degi, dinv, blocksums, N);
    k_scan2<<<1, 1024, 0, stream>>>(blocksums, blockoffs, row_start, nRed, N);
    k_scan3off<<<nRed, 256, 0, stream>>>(degi, blockoffs, row_start, hist, N);
    k_place<<<P_CHUNKS * 4, HPB, 0, stream>>>(srcp, dstp, hist, csr_src, E, CE);

    // ---- layer 1: h = (x*dinv)@W1 fused (bf16) ; h1 = relu(...)*dinv (bf16) ----
    gemm_x_fused<<<Mp / 128, 512, 0, stream>>>(x, dinv, W1t, h, N, NFEAT);
    {
        int total = N * 64;
        k_gather<NH1, true, false><<<(total + 255) / 256, 256, 0, stream>>>(
            row_start, csr_src, dinv, h, b1, h1, nullptr, N);
    }

    // ---- layer 2: h2 = h1s@W2 (bf16) ; out = gather + b2 (fp32) ----
    {
        dim3 g(NH2 / 128, Mp / 128);
        gemm_bf16<<<g, 256, 0, stream>>>(h1, W2t, h2, NH2, NH1);
    }
    {
        int total = N * 64;
        k_gather<NH2, false, true><<<(total + 255) / 256, 256, 0, stream>>>(
            row_start, csr_src, dinv, h2, b2, nullptr, out, N);
    }
}